// Round 1
// baseline (50.710 us; speedup 1.0000x reference)
//
#include <hip/hip_runtime.h>
#include <math.h>

namespace {
constexpr int   NTYPES   = 200;
constexpr float CONST_T  = 0.89776110649108887f; // exp(-0.004314*(298-273))
constexpr float RAD10_   = 0.17453292519943295f;
constexpr float RAD30_   = 0.52359877559829882f;
constexpr float RAD150_  = 2.6179938779914944f;
constexpr float RAD180_  = 3.14159265358979323f;
constexpr float ION_CORR = 0.02f + 0.05f / 1.4f;
}

__global__ __launch_bounds__(256) void electro_kernel(
    const float* __restrict__ coords,      // [N_ATOMS,3]
    const float* __restrict__ partners,    // [N_ATOMS,2,3]
    const float* __restrict__ props,       // [NTYPES,5] charged,charge,virtual,dipole,radius
    const int*   __restrict__ desc,        // [N_ATOMS,3] at_name,resnum,chain
    const int2*  __restrict__ pairs,       // [N_PAIRS,2]
    float*       __restrict__ out,
    int n)
{
    __shared__ float sp[NTYPES * 5];
    for (int t = threadIdx.x; t < NTYPES * 5; t += blockDim.x) sp[t] = props[t];
    __syncthreads();

    const int stride = gridDim.x * blockDim.x;
    for (int p = blockIdx.x * blockDim.x + threadIdx.x; p < n; p += stride) {
        const int2 ij = pairs[p];
        const int i = ij.x, j = ij.y;

        const int at1 = desc[3 * i];
        const int at2 = desc[3 * j];

        const bool rc1 = (at1 == 10) | (at1 == 11);
        const bool rc2 = (at2 == 10) | (at2 == 11);
        const bool argInv = ((at1 == 12) & ((at2 == 12) | rc2)) |
                            ((at2 == 12) & ((at1 == 12) | rc1));

        const float* __restrict__ p1 = &sp[5 * at1];
        const float* __restrict__ p2 = &sp[5 * at2];
        const bool is_charged = ((p1[0] == 1.0f) & (p2[0] == 1.0f)) | argInv;

        float energy = 0.0f;
        if (is_charged) {
            // these gathers only issue for ~16% of lanes (exec-masked)
            const int res1 = desc[3 * i + 1], ch1 = desc[3 * i + 2];
            const int res2 = desc[3 * j + 1], ch2 = desc[3 * j + 2];
            const float ax = coords[3 * i], ay = coords[3 * i + 1], az = coords[3 * i + 2];
            const float bx = coords[3 * j], by = coords[3 * j + 1], bz = coords[3 * j + 2];
            const float dx = ax - bx, dy = ay - by, dz = az - bz;
            const float dist = sqrtf(dx * dx + dy * dy + dz * dz + 1e-12f);

            const bool diff_res = (res1 != res2) | (ch1 != ch2);
            if ((dist <= 15.0f) & diff_res) {
                // ---------------- ARG (aromatic/guanidinium) path — very rare ----------------
                // pre-filter with the dist window from ang_bad before touching partners[]
                if (argInv && (dist >= 3.9f) && (dist <= 4.3f)) {
                    const float a0x = partners[6 * i],     a0y = partners[6 * i + 1], a0z = partners[6 * i + 2];
                    const float a1x = partners[6 * i + 3], a1y = partners[6 * i + 4], a1z = partners[6 * i + 5];
                    const float b0x = partners[6 * j],     b0y = partners[6 * j + 1], b0z = partners[6 * j + 2];
                    const float b1x = partners[6 * j + 3], b1y = partners[6 * j + 4], b1z = partners[6 * j + 5];
                    // n1 = cross(pA0-cA, pA1-cA)
                    const float u1x = a0x - ax, u1y = a0y - ay, u1z = a0z - az;
                    const float v1x = a1x - ax, v1y = a1y - ay, v1z = a1z - az;
                    const float n1x = u1y * v1z - u1z * v1y;
                    const float n1y = u1z * v1x - u1x * v1z;
                    const float n1z = u1x * v1y - u1y * v1x;
                    // n2 = cross(pB0-cB, pB1-cB)
                    const float u2x = b0x - bx, u2y = b0y - by, u2z = b0z - bz;
                    const float v2x = b1x - bx, v2y = b1y - by, v2z = b1z - bz;
                    const float n2x = u2y * v2z - u2z * v2y;
                    const float n2y = u2z * v2x - u2x * v2z;
                    const float n2z = u2x * v2y - u2y * v2x;

                    const float nn1 = sqrtf(n1x * n1x + n1y * n1y + n1z * n1z + 1e-12f);
                    const float nn2 = sqrtf(n2x * n2x + n2y * n2y + n2z * n2z + 1e-12f);
                    const bool m = (nn1 > 1e-6f) & (nn2 > 1e-6f);
                    float cosang = (n1x * n2x + n1y * n2y + n1z * n2z) / (nn1 * nn2);
                    cosang = fminf(fmaxf(cosang, -0.999999f), 0.999999f);
                    const float ang = acosf(cosang);
                    const bool ang_mid_bad = (ang > RAD30_) & (ang < RAD150_);
                    if (m & !ang_mid_bad) {
                        const float dsafe  = fmaxf(dist, 1e-6f);
                        const float argEpss = 332.0f / (dsafe * 8.8f * CONST_T);
                        const float temp_d  = 3.0f + fabsf(dist - 4.1f);
                        // reference quirk: compares DIST (not ang) against RAD150
                        const float corr_ang = (dist > RAD150_)
                            ? fmaxf((RAD180_ - ang) / RAD10_, 1.0f)
                            : fmaxf(dist / RAD10_, 1.0f);
                        const bool  arg_arg = (at1 == 13) & (at2 == 13); // disjoint from argInv, kept for fidelity
                        const float c2e = arg_arg ? -1.0f : -0.5f;       // c1e == 1
                        const float vk  = sqrtf(200.0f * fabsf(c2e) * ION_CORR / 298.0f);
                        energy += (1.0f / corr_ang) * c2e * argEpss *
                                  expf(-temp_d * vk) / (temp_d * temp_d);
                    }
                }

                // ---------------- kon (charged-charged inter-chain) path ----------------
                const float c1 = p1[1], c2 = p2[1];
                const bool charged_charged =
                    (c1 != 0.0f) & (c2 != 0.0f) &        // (PAD=999 never occurs in the table)
                    (p1[2] != 1.0f) & (p2[2] != 1.0f);   // ~virtual
                const bool kon_mask = charged_charged &
                    (p1[3] == 0.0f) & (p2[3] == 0.0f) &  // dipole == 0
                    (ch1 != ch2);                        // inter-chain
                if (kon_mask) {
                    const float sum_radii = p1[4] + p2[4] - 0.09f;
                    const float dd  = fmaxf(dist, sum_radii);
                    const float tk  = fmaxf(dd + dd * dd * (1.0f / 30.0f), 6.0f);
                    const float k_on = sqrtf(200.0f * fabsf(c1) * fabsf(c2) * 0.05f / 298.0f);
                    const float first  = 332.0f * c1 * c2 / (88.0f * tk * CONST_T);
                    const float second = expf(-k_on * (tk - 6.0f));
                    const float third  = 1.0f + k_on * 6.0f;
                    energy += 0.5f * first * second / third;
                }
            }
        }
        out[p] = energy;
    }
}

extern "C" void kernel_launch(void* const* d_in, const int* in_sizes, int n_in,
                              void* d_out, int out_size, void* d_ws, size_t ws_size,
                              hipStream_t stream) {
    const float* coords   = (const float*)d_in[0];
    const float* partners = (const float*)d_in[1];
    const float* props    = (const float*)d_in[2];
    const int*   desc     = (const int*)d_in[3];
    const int2*  pairs    = (const int2*)d_in[4];
    float*       out      = (float*)d_out;

    const int n = in_sizes[4] / 2;   // 4,000,000 pairs
    const int block = 256;
    int grid = (n + block - 1) / block;
    if (grid > 2048) grid = 2048;    // grid-stride; ~8 blocks/CU
    electro_kernel<<<grid, block, 0, stream>>>(coords, partners, props, desc, pairs, out, n);
}